// Round 3
// baseline (1780.414 us; speedup 1.0000x reference)
//
#include <hip/hip_runtime.h>
#include <math.h>

// Problem constants
#define BB 16
#define TT 4096
#define DD 512
#define LOUT 512

// ---------------------------------------------------------------------------
// Workspace layout (bytes):
//   wt       : 786432 floats  @ 0          (conv_w repacked [tap][k][c])
//   a_pre    : 65536 floats   @ 3145728    (pre-sigmoid logits, atomicAdd target)
//   w_main   : 65536 floats   @ 3407872    (per-t main CIF weight)
//   fire_pos : 16*1024 ints   @ 3670016
//   Fcount   : 16 ints        @ 3735552
//   zpage    : 1024 floats    @ 3735616    (zero page for conv halo rows)
// ---------------------------------------------------------------------------

__global__ void zero_ws(float* __restrict__ a_pre, float* __restrict__ zpage) {
    int idx = blockIdx.x * 256 + threadIdx.x;
    if (idx < 65536) a_pre[idx] = 0.f;
    if (idx < 1024)  zpage[idx] = 0.f;
}

__global__ void repack_w(const float* __restrict__ conv_w, float* __restrict__ wt) {
    int idx = blockIdx.x * 256 + threadIdx.x;          // over 786432
    if (idx < 786432) {
        int k = idx / 262144;
        int rem = idx - k * 262144;
        int i = rem >> 9;          // /512
        int c = rem & 511;
        // conv_w[c][i][k]  ->  wt[k][i][c]
        wt[idx] = conv_w[(c * 512 + i) * 3 + k];
    }
}

// Fused conv(K=3) GEMM + ReLU + dot(out_w).
// BM=128 (16 tr-groups x 8 rows), BN=128 (16 tc-lanes x 8 cols as 2x float4
// 64 apart), BK=16. tc = tid&15 (LOW lane bits) so the 16 lanes of a tc-group
// broadcast-share every A address -> A read straight from global via L1,
// no LDS staging for A at all. W staged in LDS; 16B-stride reads = 2-way = free.
__launch_bounds__(256, 3)
__global__ void conv_gemm(const float* __restrict__ hidden,
                          const float* __restrict__ wt,
                          const float* __restrict__ conv_b,
                          const float* __restrict__ out_w,
                          const float* __restrict__ zpage,
                          float* __restrict__ a_pre) {
    __shared__ float Ws[3 * 16 * 128];     // [tap][kk][c], 24 KB

    const int tid = threadIdx.x;
    const int tc  = tid & 15;              // low bits: broadcast group for A
    const int tr  = tid >> 4;              // row group 0..15 (8 rows each)

    const int mtile = blockIdx.x;          // 0..511
    const int b  = mtile >> 5;
    const int t0 = (mtile & 31) << 7;      // *128
    const int c0 = blockIdx.y << 7;        // *128

    // 10 row pointers (8 rows + 2-tap halo); OOB rows -> zero page
    const float* rowp[10];
    #pragma unroll
    for (int r = 0; r < 10; r++) {
        int t = t0 - 1 + 8 * tr + r;
        rowp[r] = (t >= 0 && t < TT) ? (hidden + ((size_t)b * TT + t) * DD)
                                     : zpage;
    }

    float acc[8][8];
    #pragma unroll
    for (int r = 0; r < 8; r++)
        #pragma unroll
        for (int cc = 0; cc < 8; cc++) acc[r][cc] = 0.f;

    float u[8], cb[8];
    #pragma unroll
    for (int h = 0; h < 2; h++)
        #pragma unroll
        for (int c = 0; c < 4; c++) {
            u[4 * h + c]  = out_w[c0 + 64 * h + 4 * tc + c];
            cb[4 * h + c] = conv_b[c0 + 64 * h + 4 * tc + c];
        }

    for (int kc = 0; kc < 32; kc++) {
        const int k0 = kc * 16;
        // stage W chunk: 3 taps x 16 kk x 128 c = 1536 float4, 6 per thread
        for (int i = tid; i < 1536; i += 256) {
            int tap = i >> 9;
            int rem = i & 511;
            int kk = rem >> 5;
            int cq = rem & 31;
            *(float4*)&Ws[tap * 2048 + kk * 128 + 4 * cq] =
                *(const float4*)(wt + tap * 262144 + (size_t)(k0 + kk) * 512 + c0 + 4 * cq);
        }
        __syncthreads();

        #pragma unroll
        for (int g = 0; g < 4; g++) {
            float4 af4[10];
            #pragma unroll
            for (int r = 0; r < 10; r++)
                af4[r] = *(const float4*)(rowp[r] + k0 + 4 * g);

            #pragma unroll
            for (int j = 0; j < 4; j++) {
                const int kk = 4 * g + j;
                float wf[3][8];
                #pragma unroll
                for (int tap = 0; tap < 3; tap++) {
                    *(float4*)&wf[tap][0] = *(const float4*)&Ws[tap * 2048 + kk * 128 + 4 * tc];
                    *(float4*)&wf[tap][4] = *(const float4*)&Ws[tap * 2048 + kk * 128 + 64 + 4 * tc];
                }
                #pragma unroll
                for (int tap = 0; tap < 3; tap++)
                    #pragma unroll
                    for (int r = 0; r < 8; r++) {
                        const float a = ((const float*)&af4[r + tap])[j];
                        #pragma unroll
                        for (int cc = 0; cc < 8; cc++)
                            acc[r][cc] = fmaf(a, wf[tap][cc], acc[r][cc]);
                    }
            }
        }
        __syncthreads();
    }

    // epilogue: relu(y + conv_b) dot out_w; reduce across the 16 tc lanes
    float part[8];
    #pragma unroll
    for (int r = 0; r < 8; r++) {
        float s = 0.f;
        #pragma unroll
        for (int cc = 0; cc < 8; cc++) {
            float y = acc[r][cc] + cb[cc];
            y = y > 0.f ? y : 0.f;
            s = fmaf(y, u[cc], s);
        }
        part[r] = s;
    }
    #pragma unroll
    for (int r = 0; r < 8; r++) {
        #pragma unroll
        for (int off = 1; off < 16; off <<= 1)
            part[r] += __shfl_xor(part[r], off, 16);
    }
    if (tc == 0) {
        #pragma unroll
        for (int r = 0; r < 8; r++)
            atomicAdd(&a_pre[b * TT + t0 + 8 * tr + r], part[r]);
    }
}

// Per-batch: sigmoid -> token_num -> rescale -> sequential CIF scan.
__global__ void cif_scan(const float* __restrict__ a_pre,
                         const float* __restrict__ mask,
                         const float* __restrict__ tll,
                         const float* __restrict__ out_bias,
                         float* __restrict__ out_tn,
                         float* __restrict__ out_alphas,
                         float* __restrict__ out_peak,
                         float* __restrict__ w_main,
                         int* __restrict__ fire_pos,
                         int* __restrict__ Fcount) {
    __shared__ float alpha_s[TT];
    __shared__ float wm_s[TT];
    __shared__ float fires_s[TT];
    __shared__ int   fp_s[1024];
    __shared__ double red[256];
    __shared__ float ratio_s;
    __shared__ int   F_sh;

    const int b = blockIdx.x;
    const int tid = threadIdx.x;
    const float ob = out_bias[0];

    double lsum = 0.0;
    for (int t = tid; t < TT; t += 256) {
        float a = a_pre[b * TT + t] + ob;
        float e = expf(-fabsf(a));
        float sg = (a >= 0.f) ? (1.f / (1.f + e)) : (e / (1.f + e));
        float af = sg * 1.0f - 0.0f;                 // SMOOTH_FACTOR / NOISE_THRESHOLD
        af = af > 0.f ? af : 0.f;
        af = af * mask[b * TT + t];
        alpha_s[t] = af;
        lsum += (double)af;
    }
    red[tid] = lsum;
    __syncthreads();
    for (int off = 128; off > 0; off >>= 1) {
        if (tid < off) red[tid] += red[tid + off];
        __syncthreads();
    }
    if (tid == 0) {
        float tn = (float)red[0];
        out_tn[b] = tn;
        ratio_s = tll[b] / tn;
    }
    __syncthreads();
    const float ratio = ratio_s;
    for (int t = tid; t < TT; t += 256) {
        float a = alpha_s[t] * ratio;
        alpha_s[t] = a;
        out_alphas[b * TT + t] = a;
    }
    __syncthreads();

    if (tid == 0) {
        float I = 0.f;
        int F = 0;
        for (int t = 0; t < TT; t++) {
            float a = alpha_s[t];
            float In = I + a;
            fires_s[t] = In;
            bool fire = (In >= 1.0f);
            float dist = 1.0f - I;
            wm_s[t] = fire ? dist : a;
            if (fire) {
                if (F < 1024) fp_s[F] = t;
                F++;
                I = In - 1.0f;
            } else {
                I = In;
            }
        }
        F_sh = (F > 1024) ? 1024 : F;
        Fcount[b] = F_sh;
    }
    __syncthreads();
    const int F = F_sh;
    for (int t = tid; t < TT; t += 256) {
        out_peak[b * TT + t] = fires_s[t];
        w_main[b * TT + t]   = wm_s[t];
    }
    for (int s = tid; s < F; s += 256)
        fire_pos[b * 1024 + s] = fp_s[s];
}

// acoustic_embeds[b,s,:] = spill(prev fire) + sum of main weights over the
// contiguous t-segment ending at fire_pos[s].
__global__ void cif_scatter(const float* __restrict__ hidden,
                            const float* __restrict__ alphas,   // scaled (in d_out)
                            const float* __restrict__ w_main,
                            const int* __restrict__ fire_pos,
                            const int* __restrict__ Fcount,
                            float* __restrict__ out_emb) {
    const int s = blockIdx.x;      // 0..511
    const int b = blockIdx.y;      // 0..15
    const int tid = threadIdx.x;   // 0..127 -> d = 4*tid
    const int F = Fcount[b];

    float4 acc = make_float4(0.f, 0.f, 0.f, 0.f);
    if (s < F) {
        const int t_hi = fire_pos[b * 1024 + s];
        const int t_lo = (s > 0) ? fire_pos[b * 1024 + s - 1] : 0;
        for (int t = t_lo; t <= t_hi; t++) {
            float w;
            if (s > 0 && t == t_lo)
                w = alphas[b * TT + t] - w_main[b * TT + t];   // remainds (spill)
            else
                w = w_main[b * TT + t];
            const float4 h = *(const float4*)(hidden + ((size_t)(b * TT + t)) * DD + 4 * tid);
            acc.x = fmaf(w, h.x, acc.x);
            acc.y = fmaf(w, h.y, acc.y);
            acc.z = fmaf(w, h.z, acc.z);
            acc.w = fmaf(w, h.w, acc.w);
        }
    }
    *(float4*)(out_emb + ((size_t)(b * LOUT + s)) * DD + 4 * tid) = acc;
}

extern "C" void kernel_launch(void* const* d_in, const int* in_sizes, int n_in,
                              void* d_out, int out_size, void* d_ws, size_t ws_size,
                              hipStream_t stream) {
    const float* hidden  = (const float*)d_in[0];   // (16,4096,512)
    const float* mask    = (const float*)d_in[1];   // (16,1,4096)
    const float* tll     = (const float*)d_in[2];   // (16,1)
    const float* conv_w  = (const float*)d_in[3];   // (512,512,3)
    const float* conv_b  = (const float*)d_in[4];   // (512,)
    const float* out_w   = (const float*)d_in[5];   // (1,512)
    const float* out_b   = (const float*)d_in[6];   // (1,)

    float* out        = (float*)d_out;
    float* out_emb    = out;                         // 16*512*512
    float* out_tn     = out + 4194304;               // 16
    float* out_alphas = out + 4194320;               // 16*4096
    float* out_peak   = out + 4259856;               // 16*4096

    char* ws = (char*)d_ws;
    float* wt       = (float*)(ws);                  // 786432 f
    float* a_pre    = (float*)(ws + 3145728);        // 65536 f
    float* w_main   = (float*)(ws + 3407872);        // 65536 f
    int*   fire_pos = (int*)(ws + 3670016);          // 16*1024 int
    int*   Fcount   = (int*)(ws + 3735552);          // 16 int
    float* zpage    = (float*)(ws + 3735616);        // 1024 f zeros

    zero_ws<<<256, 256, 0, stream>>>(a_pre, zpage);
    repack_w<<<3072, 256, 0, stream>>>(conv_w, wt);
    conv_gemm<<<dim3(512, 4), 256, 0, stream>>>(hidden, wt, conv_b, out_w, zpage, a_pre);
    cif_scan<<<16, 256, 0, stream>>>(a_pre, mask, tll, out_b,
                                     out_tn, out_alphas, out_peak,
                                     w_main, fire_pos, Fcount);
    cif_scatter<<<dim3(512, 16), 128, 0, stream>>>(hidden, out_alphas, w_main,
                                                   fire_pos, Fcount, out_emb);
}

// Round 4
// 1716.310 us; speedup vs baseline: 1.0374x; 1.0374x over previous
//
#include <hip/hip_runtime.h>
#include <math.h>

// Problem constants
#define BB 16
#define TT 4096
#define DD 512
#define LOUT 512

// ---------------------------------------------------------------------------
// Workspace layout (bytes):
//   wt       : 786432 floats  @ 0          (conv_w repacked [tap][k][c])
//   a_pre    : 65536 floats   @ 3145728    (pre-sigmoid logits, atomicAdd target)
//   w_main   : 65536 floats   @ 3407872    (per-t main CIF weight)
//   fire_pos : 16*1024 ints   @ 3670016
//   Fcount   : 16 ints        @ 3735552
//   zpage    : 1024 floats    @ 3735616    (zero page for conv halo rows)
// ---------------------------------------------------------------------------

__global__ void zero_ws(float* __restrict__ a_pre, float* __restrict__ zpage) {
    int idx = blockIdx.x * 256 + threadIdx.x;
    if (idx < 65536) a_pre[idx] = 0.f;
    if (idx < 1024)  zpage[idx] = 0.f;
}

__global__ void repack_w(const float* __restrict__ conv_w, float* __restrict__ wt) {
    int idx = blockIdx.x * 256 + threadIdx.x;          // over 786432
    if (idx < 786432) {
        int k = idx / 262144;
        int rem = idx - k * 262144;
        int i = rem >> 9;          // /512
        int c = rem & 511;
        // conv_w[c][i][k]  ->  wt[k][i][c]
        wt[idx] = conv_w[(c * 512 + i) * 3 + k];
    }
}

// Fused conv(K=3) GEMM + ReLU + dot(out_w).
// BM=128 (16 tr-groups x 8 rows), BN=64 (16 tc-lanes x 4 cols), BK=16.
// tc = tid&15 (LOW lane bits): the 16 lanes of a tc-group broadcast-share every
// A address -> A read straight from global via L1 (no LDS-A, no conflicts).
// W staged in LDS; 16B-stride b128 reads = 2-way aliasing = free (m136).
// 8x4 acc keeps live VGPRs ~115 < the (256,3) cap of ~170 -> no scratch spill
// (R3's 8x8 tile needed ~190 and spilled: WRITE_SIZE 86 MB, 66% VALUBusy).
__launch_bounds__(256, 3)
__global__ void conv_gemm(const float* __restrict__ hidden,
                          const float* __restrict__ wt,
                          const float* __restrict__ conv_b,
                          const float* __restrict__ out_w,
                          const float* __restrict__ zpage,
                          float* __restrict__ a_pre) {
    __shared__ float Ws[3 * 16 * 64];      // [tap][kk][c], 12 KB

    const int tid = threadIdx.x;
    const int tc  = tid & 15;              // low bits: broadcast group for A
    const int tr  = tid >> 4;              // row group 0..15 (8 rows each)

    const int c0 = blockIdx.x << 6;        // 8 c-tiles, fast dim -> XCD spread
    const int mtile = blockIdx.y;          // 0..511
    const int b  = mtile >> 5;
    const int t0 = (mtile & 31) << 7;      // *128

    // 10 row pointers (8 rows + 2-tap halo); OOB rows -> zero page
    const float* rowp[10];
    #pragma unroll
    for (int r = 0; r < 10; r++) {
        int t = t0 - 1 + 8 * tr + r;
        rowp[r] = (t >= 0 && t < TT) ? (hidden + ((size_t)b * TT + t) * DD)
                                     : zpage;
    }

    float acc[8][4];
    #pragma unroll
    for (int r = 0; r < 8; r++)
        #pragma unroll
        for (int c = 0; c < 4; c++) acc[r][c] = 0.f;

    float u[4], cb[4];
    #pragma unroll
    for (int c = 0; c < 4; c++) {
        u[c]  = out_w[c0 + 4 * tc + c];
        cb[c] = conv_b[c0 + 4 * tc + c];
    }

    for (int kc = 0; kc < 32; kc++) {
        const int k0 = kc * 16;
        // stage W chunk: 3 taps x 16 kk x 64 c = 768 float4, 3 per thread
        for (int i = tid; i < 768; i += 256) {
            int tap = i >> 8;
            int rem = i & 255;
            int kk = rem >> 4;
            int cq = rem & 15;
            *(float4*)&Ws[tap * 1024 + kk * 64 + 4 * cq] =
                *(const float4*)(wt + tap * 262144 + (size_t)(k0 + kk) * 512 + c0 + 4 * cq);
        }
        __syncthreads();

        #pragma unroll
        for (int g = 0; g < 4; g++) {
            float4 af4[10];
            #pragma unroll
            for (int r = 0; r < 10; r++)
                af4[r] = *(const float4*)(rowp[r] + k0 + 4 * g);

            #pragma unroll
            for (int j = 0; j < 4; j++) {
                const int kk = 4 * g + j;
                float wf[3][4];
                #pragma unroll
                for (int tap = 0; tap < 3; tap++)
                    *(float4*)&wf[tap][0] = *(const float4*)&Ws[tap * 1024 + kk * 64 + 4 * tc];
                #pragma unroll
                for (int tap = 0; tap < 3; tap++)
                    #pragma unroll
                    for (int r = 0; r < 8; r++) {
                        const float a = ((const float*)&af4[r + tap])[j];
                        #pragma unroll
                        for (int cc = 0; cc < 4; cc++)
                            acc[r][cc] = fmaf(a, wf[tap][cc], acc[r][cc]);
                    }
            }
        }
        __syncthreads();
    }

    // epilogue: relu(y + conv_b) dot out_w; reduce across the 16 tc lanes
    float part[8];
    #pragma unroll
    for (int r = 0; r < 8; r++) {
        float s = 0.f;
        #pragma unroll
        for (int cc = 0; cc < 4; cc++) {
            float y = acc[r][cc] + cb[cc];
            y = y > 0.f ? y : 0.f;
            s = fmaf(y, u[cc], s);
        }
        part[r] = s;
    }
    #pragma unroll
    for (int r = 0; r < 8; r++) {
        #pragma unroll
        for (int off = 1; off < 16; off <<= 1)
            part[r] += __shfl_xor(part[r], off, 16);
    }
    if (tc == 0) {
        #pragma unroll
        for (int r = 0; r < 8; r++)
            atomicAdd(&a_pre[b * TT + t0 + 8 * tr + r], part[r]);
    }
}

// Per-batch: sigmoid -> token_num -> rescale -> sequential CIF scan.
// Serial scan is software-pipelined: prefetch the next 8 alphas (2x b128)
// while the current 8 run as a pure-register dependency chain.
__global__ void cif_scan(const float* __restrict__ a_pre,
                         const float* __restrict__ mask,
                         const float* __restrict__ tll,
                         const float* __restrict__ out_bias,
                         float* __restrict__ out_tn,
                         float* __restrict__ out_alphas,
                         float* __restrict__ out_peak,
                         float* __restrict__ w_main,
                         int* __restrict__ fire_pos,
                         int* __restrict__ Fcount) {
    __shared__ float alpha_s[TT];
    __shared__ float wm_s[TT];
    __shared__ float fires_s[TT];
    __shared__ int   fp_s[1024];
    __shared__ double red[256];
    __shared__ float ratio_s;
    __shared__ int   F_sh;

    const int b = blockIdx.x;
    const int tid = threadIdx.x;
    const float ob = out_bias[0];

    double lsum = 0.0;
    for (int t = tid; t < TT; t += 256) {
        float a = a_pre[b * TT + t] + ob;
        float e = expf(-fabsf(a));
        float sg = (a >= 0.f) ? (1.f / (1.f + e)) : (e / (1.f + e));
        float af = sg * 1.0f - 0.0f;                 // SMOOTH_FACTOR / NOISE_THRESHOLD
        af = af > 0.f ? af : 0.f;
        af = af * mask[b * TT + t];
        alpha_s[t] = af;
        lsum += (double)af;
    }
    red[tid] = lsum;
    __syncthreads();
    for (int off = 128; off > 0; off >>= 1) {
        if (tid < off) red[tid] += red[tid + off];
        __syncthreads();
    }
    if (tid == 0) {
        float tn = (float)red[0];
        out_tn[b] = tn;
        ratio_s = tll[b] / tn;
    }
    __syncthreads();
    const float ratio = ratio_s;
    for (int t = tid; t < TT; t += 256) {
        float a = alpha_s[t] * ratio;
        alpha_s[t] = a;
        out_alphas[b * TT + t] = a;
    }
    __syncthreads();

    if (tid == 0) {
        float I = 0.f;
        int F = 0;
        float4 n0 = *(const float4*)&alpha_s[0];
        float4 n1 = *(const float4*)&alpha_s[4];
        for (int t8 = 0; t8 < TT; t8 += 8) {
            float av[8];
            *(float4*)&av[0] = n0;
            *(float4*)&av[4] = n1;
            if (t8 + 8 < TT) {
                n0 = *(const float4*)&alpha_s[t8 + 8];
                n1 = *(const float4*)&alpha_s[t8 + 12];
            }
            #pragma unroll
            for (int j = 0; j < 8; j++) {
                float a = av[j];
                float In = I + a;
                fires_s[t8 + j] = In;
                bool fire = (In >= 1.0f);
                wm_s[t8 + j] = fire ? (1.0f - I) : a;
                int Fc = (F < 1023) ? F : 1023;
                fp_s[Fc] = t8 + j;               // unconditional; kept only if fire
                F += fire ? 1 : 0;
                I = fire ? (In - 1.0f) : In;
            }
        }
        F_sh = (F > 1024) ? 1024 : F;
        Fcount[b] = F_sh;
    }
    __syncthreads();
    const int F = F_sh;
    for (int t = tid; t < TT; t += 256) {
        out_peak[b * TT + t] = fires_s[t];
        w_main[b * TT + t]   = wm_s[t];
    }
    for (int s = tid; s < F; s += 256)
        fire_pos[b * 1024 + s] = fp_s[s];
}

// acoustic_embeds[b,s,:] = spill(prev fire) + sum of main weights over the
// contiguous t-segment ending at fire_pos[s].
__global__ void cif_scatter(const float* __restrict__ hidden,
                            const float* __restrict__ alphas,   // scaled (in d_out)
                            const float* __restrict__ w_main,
                            const int* __restrict__ fire_pos,
                            const int* __restrict__ Fcount,
                            float* __restrict__ out_emb) {
    const int s = blockIdx.x;      // 0..511
    const int b = blockIdx.y;      // 0..15
    const int tid = threadIdx.x;   // 0..127 -> d = 4*tid
    const int F = Fcount[b];

    float4 acc = make_float4(0.f, 0.f, 0.f, 0.f);
    if (s < F) {
        const int t_hi = fire_pos[b * 1024 + s];
        const int t_lo = (s > 0) ? fire_pos[b * 1024 + s - 1] : 0;
        for (int t = t_lo; t <= t_hi; t++) {
            float w;
            if (s > 0 && t == t_lo)
                w = alphas[b * TT + t] - w_main[b * TT + t];   // remainds (spill)
            else
                w = w_main[b * TT + t];
            const float4 h = *(const float4*)(hidden + ((size_t)(b * TT + t)) * DD + 4 * tid);
            acc.x = fmaf(w, h.x, acc.x);
            acc.y = fmaf(w, h.y, acc.y);
            acc.z = fmaf(w, h.z, acc.z);
            acc.w = fmaf(w, h.w, acc.w);
        }
    }
    *(float4*)(out_emb + ((size_t)(b * LOUT + s)) * DD + 4 * tid) = acc;
}

extern "C" void kernel_launch(void* const* d_in, const int* in_sizes, int n_in,
                              void* d_out, int out_size, void* d_ws, size_t ws_size,
                              hipStream_t stream) {
    const float* hidden  = (const float*)d_in[0];   // (16,4096,512)
    const float* mask    = (const float*)d_in[1];   // (16,1,4096)
    const float* tll     = (const float*)d_in[2];   // (16,1)
    const float* conv_w  = (const float*)d_in[3];   // (512,512,3)
    const float* conv_b  = (const float*)d_in[4];   // (512,)
    const float* out_w   = (const float*)d_in[5];   // (1,512)
    const float* out_b   = (const float*)d_in[6];   // (1,)

    float* out        = (float*)d_out;
    float* out_emb    = out;                         // 16*512*512
    float* out_tn     = out + 4194304;               // 16
    float* out_alphas = out + 4194320;               // 16*4096
    float* out_peak   = out + 4259856;               // 16*4096

    char* ws = (char*)d_ws;
    float* wt       = (float*)(ws);                  // 786432 f
    float* a_pre    = (float*)(ws + 3145728);        // 65536 f
    float* w_main   = (float*)(ws + 3407872);        // 65536 f
    int*   fire_pos = (int*)(ws + 3670016);          // 16*1024 int
    int*   Fcount   = (int*)(ws + 3735552);          // 16 int
    float* zpage    = (float*)(ws + 3735616);        // 1024 f zeros

    zero_ws<<<256, 256, 0, stream>>>(a_pre, zpage);
    repack_w<<<3072, 256, 0, stream>>>(conv_w, wt);
    conv_gemm<<<dim3(8, 512), 256, 0, stream>>>(hidden, wt, conv_b, out_w, zpage, a_pre);
    cif_scan<<<16, 256, 0, stream>>>(a_pre, mask, tll, out_b,
                                     out_tn, out_alphas, out_peak,
                                     w_main, fire_pos, Fcount);
    cif_scatter<<<dim3(512, 16), 128, 0, stream>>>(hidden, out_alphas, w_main,
                                                   fire_pos, Fcount, out_emb);
}

// Round 5
// 851.022 us; speedup vs baseline: 2.0921x; 2.0168x over previous
//
#include <hip/hip_runtime.h>
#include <math.h>

// Problem constants
#define BB 16
#define TT 4096
#define DD 512
#define LOUT 512

typedef __attribute__((ext_vector_type(8))) _Float16 half8;
typedef __attribute__((ext_vector_type(4))) float floatx4;

// ---------------------------------------------------------------------------
// Workspace layout (bytes), total ~131.6 MB:
//   A_hi    : _Float16[33554432] @ 0          (hidden hi split)
//   A_lo    : _Float16[33554432] @ 67108864   (hidden lo split)
//   B_hi    : _Float16[786432]   @ 134217728  (conv_w hi, [tap][c][i])
//   B_lo    : _Float16[786432]   @ 135790592
//   a_pre   : float[65536]       @ 137363456
//   w_main  : float[65536]       @ 137625600
//   fire_pos: int[16384]         @ 137887744
//   Fcount  : int[16]            @ 137953280
//   zpage16 : _Float16[512]      @ 137953344  (zero page, conv halo rows)
// ---------------------------------------------------------------------------

__global__ void zero_ws(float* __restrict__ a_pre, _Float16* __restrict__ zp) {
    int idx = blockIdx.x * 256 + threadIdx.x;
    if (idx < 65536) a_pre[idx] = 0.f;
    if (idx < 512)   zp[idx] = (_Float16)0.f;
}

// hidden fp32 -> f16 hi + f16 lo (x = hi + lo + O(2^-22 x))
__global__ void split_hidden(const float* __restrict__ hidden,
                             _Float16* __restrict__ A_hi,
                             _Float16* __restrict__ A_lo) {
    int idx = blockIdx.x * 256 + threadIdx.x;    // 4194304 threads, 8 elems each
    const float4* src = (const float4*)(hidden + 8 * (size_t)idx);
    float4 v0 = src[0], v1 = src[1];
    float x[8] = {v0.x, v0.y, v0.z, v0.w, v1.x, v1.y, v1.z, v1.w};
    _Float16 hi[8], lo[8];
    #pragma unroll
    for (int j = 0; j < 8; j++) {
        hi[j] = (_Float16)x[j];
        lo[j] = (_Float16)(x[j] - (float)hi[j]);
    }
    *(half8*)(A_hi + 8 * (size_t)idx) = *(half8*)hi;
    *(half8*)(A_lo + 8 * (size_t)idx) = *(half8*)lo;
}

// conv_w[c][i][tap] fp32 -> B_hi/B_lo [tap][c][i] f16 (B^T layout: rows=c, cols=i)
__global__ void repack_wsplit(const float* __restrict__ conv_w,
                              _Float16* __restrict__ B_hi,
                              _Float16* __restrict__ B_lo) {
    int idx = blockIdx.x * 256 + threadIdx.x;    // over 786432
    if (idx < 786432) {
        int tap = idx / 262144;
        int rem = idx - tap * 262144;
        int c = rem >> 9;
        int i = rem & 511;
        float v = conv_w[(c * 512 + i) * 3 + tap];
        _Float16 h = (_Float16)v;
        B_hi[idx] = h;
        B_lo[idx] = (_Float16)(v - (float)h);
    }
}

#define GLL16(g, l) __builtin_amdgcn_global_load_lds( \
    (const __attribute__((address_space(1))) void*)(g), \
    (__attribute__((address_space(3))) void*)(l), 16, 0, 0)

// Split-f16 MFMA conv-GEMM + fused relu-dot epilogue.
// C = Ahi*Bhi + Ahi*Blo + Alo*Bhi  (3 passes over K=1536, fp32 accumulate)
// Block tile 128(M)x128(N), 4 waves, wave tile 64x64 = 4x4 frags of 16x16x32.
__launch_bounds__(256, 2)
__global__ void mfma_gemm(const _Float16* __restrict__ A_hi,
                          const _Float16* __restrict__ A_lo,
                          const _Float16* __restrict__ B_hi,
                          const _Float16* __restrict__ B_lo,
                          const _Float16* __restrict__ zp,
                          const float* __restrict__ conv_b,
                          const float* __restrict__ out_w,
                          float* __restrict__ a_pre) {
    __shared__ _Float16 ldsA[128 * 32];   // [row][32 k-elems] = 64 B rows, 8 KB
    __shared__ _Float16 ldsB[128 * 32];   // [c-row][32 k-elems], 8 KB

    const int tid  = threadIdx.x;
    const int w    = tid >> 6;            // wave 0..3
    const int lane = tid & 63;
    const int wm   = w >> 1;              // wave row 0..1
    const int wn   = w & 1;               // wave col 0..1

    const int nt = blockIdx.x & 3;        // N-tile (c0), consecutive blocks share A
    const int mt = blockIdx.x >> 2;       // 0..511
    const int b  = mt >> 5;
    const int t0 = (mt & 31) << 7;
    const int c0 = nt << 7;

    // staging lane geometry: lane -> row (lane>>2), 16B chunk (lane&3)
    const int srow  = lane >> 2;          // 0..15
    const int schk  = lane & 3;           // 0..3 (8 f16 each)

    floatx4 acc[4][4];
    #pragma unroll
    for (int mi = 0; mi < 4; mi++)
        #pragma unroll
        for (int ni = 0; ni < 4; ni++)
            acc[mi][ni] = (floatx4)(0.f);

    // epilogue constants: col n = c0 + 64*wn + 16*ni + (lane&15)
    float u_n[4], cb_n[4];
    #pragma unroll
    for (int ni = 0; ni < 4; ni++) {
        int n = c0 + 64 * wn + 16 * ni + (lane & 15);
        u_n[ni]  = out_w[n];
        cb_n[ni] = conv_b[n];
    }

    // LDS frag pointers (fixed all kernel): row*64B + quad*16B
    const _Float16* afp[4];
    const _Float16* bfp[4];
    #pragma unroll
    for (int i = 0; i < 4; i++) {
        afp[i] = ldsA + (64 * wm + 16 * i + (lane & 15)) * 32 + (lane >> 4) * 8;
        bfp[i] = ldsB + (64 * wn + 16 * i + (lane & 15)) * 32 + (lane >> 4) * 8;
    }
    // LDS staging dest bases (wave-uniform): wave stages rows [32w, 32w+32)
    _Float16* ldsA_d0 = ldsA + (32 * w) * 32;
    _Float16* ldsA_d1 = ldsA + (32 * w + 16) * 32;
    _Float16* ldsB_d0 = ldsB + (32 * w) * 32;
    _Float16* ldsB_d1 = ldsB + (32 * w + 16) * 32;

    const _Float16* Ap[3] = {A_hi, A_hi, A_lo};
    const _Float16* Bp[3] = {B_hi, B_lo, B_hi};

    for (int p = 0; p < 3; p++) {
        for (int tap = 0; tap < 3; tap++) {
            // per-lane global pointers for this (p, tap)
            const char* ag[2];
            const char* bg[2];
            #pragma unroll
            for (int q = 0; q < 2; q++) {
                int r = 32 * w + 16 * q + srow;
                int t = t0 + r - 1 + tap;
                const _Float16* arow = (t >= 0 && t < TT)
                    ? (Ap[p] + ((size_t)b * TT + t) * DD) : zp;
                ag[q] = (const char*)(arow + schk * 8);
                int c = c0 + r;
                bg[q] = (const char*)(Bp[p] + (size_t)tap * 262144 + (size_t)c * DD + schk * 8);
            }
            for (int kt4 = 0; kt4 < 4; kt4++) {
                #pragma unroll
                for (int j = 0; j < 4; j++) {
                    const int off = j * 64;          // 32 f16 per k-step
                    GLL16(ag[0] + off, ldsA_d0);
                    GLL16(ag[1] + off, ldsA_d1);
                    GLL16(bg[0] + off, ldsB_d0);
                    GLL16(bg[1] + off, ldsB_d1);
                    __syncthreads();
                    half8 af[4], bf[4];
                    #pragma unroll
                    for (int i = 0; i < 4; i++) {
                        af[i] = *(const half8*)afp[i];
                        bf[i] = *(const half8*)bfp[i];
                    }
                    #pragma unroll
                    for (int mi = 0; mi < 4; mi++)
                        #pragma unroll
                        for (int ni = 0; ni < 4; ni++)
                            acc[mi][ni] = __builtin_amdgcn_mfma_f32_16x16x32_f16(
                                af[mi], bf[ni], acc[mi][ni], 0, 0, 0);
                    __syncthreads();
                }
                ag[0] += 256; ag[1] += 256; bg[0] += 256; bg[1] += 256;
            }
        }
    }

    // epilogue: s[mi][reg] = sum_ni relu(acc + cb)*u ; reduce over lane&15 ; atomic
    float s[4][4];
    #pragma unroll
    for (int mi = 0; mi < 4; mi++)
        #pragma unroll
        for (int rg = 0; rg < 4; rg++) {
            float t = 0.f;
            #pragma unroll
            for (int ni = 0; ni < 4; ni++) {
                float y = acc[mi][ni][rg] + cb_n[ni];
                y = y > 0.f ? y : 0.f;
                t = fmaf(y, u_n[ni], t);
            }
            s[mi][rg] = t;
        }
    #pragma unroll
    for (int mi = 0; mi < 4; mi++)
        #pragma unroll
        for (int rg = 0; rg < 4; rg++) {
            #pragma unroll
            for (int off = 1; off < 16; off <<= 1)
                s[mi][rg] += __shfl_xor(s[mi][rg], off);
        }
    if ((lane & 15) == 0) {
        const int q = lane >> 4;
        #pragma unroll
        for (int mi = 0; mi < 4; mi++)
            #pragma unroll
            for (int rg = 0; rg < 4; rg++) {
                int m = 64 * wm + 16 * mi + 4 * q + rg;
                atomicAdd(&a_pre[b * TT + t0 + m], s[mi][rg]);
            }
    }
}

// Per-batch: sigmoid -> token_num -> rescale -> sequential CIF scan (pipelined).
__global__ void cif_scan(const float* __restrict__ a_pre,
                         const float* __restrict__ mask,
                         const float* __restrict__ tll,
                         const float* __restrict__ out_bias,
                         float* __restrict__ out_tn,
                         float* __restrict__ out_alphas,
                         float* __restrict__ out_peak,
                         float* __restrict__ w_main,
                         int* __restrict__ fire_pos,
                         int* __restrict__ Fcount) {
    __shared__ float alpha_s[TT];
    __shared__ float wm_s[TT];
    __shared__ float fires_s[TT];
    __shared__ int   fp_s[1024];
    __shared__ double red[256];
    __shared__ float ratio_s;
    __shared__ int   F_sh;

    const int b = blockIdx.x;
    const int tid = threadIdx.x;
    const float ob = out_bias[0];

    double lsum = 0.0;
    for (int t = tid; t < TT; t += 256) {
        float a = a_pre[b * TT + t] + ob;
        float e = expf(-fabsf(a));
        float sg = (a >= 0.f) ? (1.f / (1.f + e)) : (e / (1.f + e));
        float af = sg;
        af = af > 0.f ? af : 0.f;
        af = af * mask[b * TT + t];
        alpha_s[t] = af;
        lsum += (double)af;
    }
    red[tid] = lsum;
    __syncthreads();
    for (int off = 128; off > 0; off >>= 1) {
        if (tid < off) red[tid] += red[tid + off];
        __syncthreads();
    }
    if (tid == 0) {
        float tn = (float)red[0];
        out_tn[b] = tn;
        ratio_s = tll[b] / tn;
    }
    __syncthreads();
    const float ratio = ratio_s;
    for (int t = tid; t < TT; t += 256) {
        float a = alpha_s[t] * ratio;
        alpha_s[t] = a;
        out_alphas[b * TT + t] = a;
    }
    __syncthreads();

    if (tid == 0) {
        float I = 0.f;
        int F = 0;
        float4 n0 = *(const float4*)&alpha_s[0];
        float4 n1 = *(const float4*)&alpha_s[4];
        for (int t8 = 0; t8 < TT; t8 += 8) {
            float av[8];
            *(float4*)&av[0] = n0;
            *(float4*)&av[4] = n1;
            if (t8 + 8 < TT) {
                n0 = *(const float4*)&alpha_s[t8 + 8];
                n1 = *(const float4*)&alpha_s[t8 + 12];
            }
            #pragma unroll
            for (int j = 0; j < 8; j++) {
                float a = av[j];
                float In = I + a;
                fires_s[t8 + j] = In;
                bool fire = (In >= 1.0f);
                wm_s[t8 + j] = fire ? (1.0f - I) : a;
                int Fc = (F < 1023) ? F : 1023;
                fp_s[Fc] = t8 + j;
                F += fire ? 1 : 0;
                I = fire ? (In - 1.0f) : In;
            }
        }
        F_sh = (F > 1024) ? 1024 : F;
        Fcount[b] = F_sh;
    }
    __syncthreads();
    const int F = F_sh;
    for (int t = tid; t < TT; t += 256) {
        out_peak[b * TT + t] = fires_s[t];
        w_main[b * TT + t]   = wm_s[t];
    }
    for (int s = tid; s < F; s += 256)
        fire_pos[b * 1024 + s] = fp_s[s];
}

// acoustic_embeds[b,s,:] = spill(prev fire) + sum over contiguous t-segment.
__global__ void cif_scatter(const float* __restrict__ hidden,
                            const float* __restrict__ alphas,
                            const float* __restrict__ w_main,
                            const int* __restrict__ fire_pos,
                            const int* __restrict__ Fcount,
                            float* __restrict__ out_emb) {
    const int s = blockIdx.x;
    const int b = blockIdx.y;
    const int tid = threadIdx.x;   // 0..127 -> d = 4*tid
    const int F = Fcount[b];

    float4 acc = make_float4(0.f, 0.f, 0.f, 0.f);
    if (s < F) {
        const int t_hi = fire_pos[b * 1024 + s];
        const int t_lo = (s > 0) ? fire_pos[b * 1024 + s - 1] : 0;
        for (int t = t_lo; t <= t_hi; t++) {
            float w;
            if (s > 0 && t == t_lo)
                w = alphas[b * TT + t] - w_main[b * TT + t];
            else
                w = w_main[b * TT + t];
            const float4 h = *(const float4*)(hidden + ((size_t)(b * TT + t)) * DD + 4 * tid);
            acc.x = fmaf(w, h.x, acc.x);
            acc.y = fmaf(w, h.y, acc.y);
            acc.z = fmaf(w, h.z, acc.z);
            acc.w = fmaf(w, h.w, acc.w);
        }
    }
    *(float4*)(out_emb + ((size_t)(b * LOUT + s)) * DD + 4 * tid) = acc;
}

extern "C" void kernel_launch(void* const* d_in, const int* in_sizes, int n_in,
                              void* d_out, int out_size, void* d_ws, size_t ws_size,
                              hipStream_t stream) {
    const float* hidden  = (const float*)d_in[0];
    const float* mask    = (const float*)d_in[1];
    const float* tll     = (const float*)d_in[2];
    const float* conv_w  = (const float*)d_in[3];
    const float* conv_b  = (const float*)d_in[4];
    const float* out_w   = (const float*)d_in[5];
    const float* out_b   = (const float*)d_in[6];

    float* out        = (float*)d_out;
    float* out_emb    = out;
    float* out_tn     = out + 4194304;
    float* out_alphas = out + 4194320;
    float* out_peak   = out + 4259856;

    char* ws = (char*)d_ws;
    _Float16* A_hi   = (_Float16*)(ws);
    _Float16* A_lo   = (_Float16*)(ws + 67108864);
    _Float16* B_hi   = (_Float16*)(ws + 134217728);
    _Float16* B_lo   = (_Float16*)(ws + 135790592);
    float* a_pre     = (float*)(ws + 137363456);
    float* w_main    = (float*)(ws + 137625600);
    int*   fire_pos  = (int*)(ws + 137887744);
    int*   Fcount    = (int*)(ws + 137953280);
    _Float16* zpage  = (_Float16*)(ws + 137953344);

    zero_ws<<<256, 256, 0, stream>>>(a_pre, zpage);
    split_hidden<<<16384, 256, 0, stream>>>(hidden, A_hi, A_lo);
    repack_wsplit<<<3072, 256, 0, stream>>>(conv_w, B_hi, B_lo);
    mfma_gemm<<<2048, 256, 0, stream>>>(A_hi, A_lo, B_hi, B_lo, zpage,
                                        conv_b, out_w, a_pre);
    cif_scan<<<16, 256, 0, stream>>>(a_pre, mask, tll, out_b,
                                     out_tn, out_alphas, out_peak,
                                     w_main, fire_pos, Fcount);
    cif_scatter<<<dim3(512, 16), 128, 0, stream>>>(hidden, out_alphas, w_main,
                                                   fire_pos, Fcount, out_emb);
}